// Round 4
// baseline (450.382 us; speedup 1.0000x reference)
//
#include <hip/hip_runtime.h>
#include <hip/hip_bf16.h>

#define NB 4
#define CH 256
#define HH 64
#define WW 64
#define NPIX 4096      // HH*WW
#define OH 62
#define NPATCH 3844    // 62*62
#define KDIM 256       // == CH
#define EPSN 1e-12f

// argmax LDS staging geometry: 2 strips of p-space (pr<32 | pr>=32),
// staged cols = 2048 + 130 halo, rounded to 2184 (mult of 8 for uint4)
#define SCOLS 2184

typedef __attribute__((ext_vector_type(8))) short short8;
typedef __attribute__((ext_vector_type(4))) float f32x4;

__device__ __forceinline__ float bf16_to_f32(unsigned short u) {
    return __uint_as_float((unsigned)u << 16);
}
__device__ __forceinline__ unsigned short f32_to_bf16(float f) {
    __hip_bfloat16 h = __float2bfloat16(f);
    return *(unsigned short*)&h;
}

// ---- K1 (fused prep): read inputs ONCE; per-pixel ss + inv-norm; normalized bf16
// ---- transpose (C,pix)->(pix,C).  Grid (64 pixtiles, 8 = b*2+which), 256 thr.
__global__ __launch_bounds__(256) void k_prep(const float* __restrict__ pred,
                                              const float* __restrict__ tgt,
                                              __hip_bfloat16* __restrict__ Xn,
                                              __hip_bfloat16* __restrict__ Tn,
                                              float* __restrict__ ssP, float* __restrict__ invP,
                                              float* __restrict__ ssT, float* __restrict__ invT) {
    const int bz = blockIdx.y;            // 0..7
    const int b = bz >> 1, which = bz & 1;
    const float* src = (which ? tgt : pred) + (size_t)b * CH * NPIX;
    unsigned short* dst = (unsigned short*)((which ? Tn : Xn) + (size_t)b * NPIX * CH);
    float* ss_g  = (which ? ssT  : ssP)  + b * NPIX;
    float* inv_g = (which ? invT : invP) + b * NPIX;
    const int pix0 = blockIdx.x * 64;
    const int t = threadIdx.x, lane = t & 63, wv = t >> 6;

    __shared__ unsigned short stage[CH][65];   // bf16, +1 pad
    __shared__ float partial[4][64];
    __shared__ float inv_s[64];

    float ssacc = 0.f;
#pragma unroll 8
    for (int cc = 0; cc < 64; ++cc) {
        int c = wv * 64 + cc;
        float v = src[(size_t)c * NPIX + pix0 + lane];
        ssacc += v * v;
        stage[c][lane] = f32_to_bf16(v);
    }
    partial[wv][lane] = ssacc;
    __syncthreads();
    if (t < 64) {
        float ss = partial[0][t] + partial[1][t] + partial[2][t] + partial[3][t];
        float inv = 1.f / fmaxf(sqrtf(ss), EPSN);
        ss_g[pix0 + t] = ss;
        inv_g[pix0 + t] = inv;
        inv_s[t] = inv;
    }
    __syncthreads();
    for (int p = wv; p < 64; p += 4) {
        float iv = inv_s[p];
#pragma unroll
        for (int cb = 0; cb < 4; ++cb) {
            int c = cb * 64 + lane;
            float v = bf16_to_f32(stage[c][p]) * iv;
            dst[(size_t)(pix0 + p) * CH + c] = f32_to_bf16(v);
        }
    }
}

// ---------------- K2: D = Xn * Tn^T  (4096x4096, K=256, bf16 MFMA, bf16 OUTPUT) ----------------
__device__ __forceinline__ void gload_lds16(const void* g, void* l) {
    __builtin_amdgcn_global_load_lds(
        (const __attribute__((address_space(1))) void*)g,
        (__attribute__((address_space(3))) void*)l, 16, 0, 0);
}

__global__ __launch_bounds__(256) void k_gemm(const __hip_bfloat16* __restrict__ A,
                                              const __hip_bfloat16* __restrict__ Bm,
                                              unsigned short* __restrict__ D) {
    __shared__ short As[128 * 32];   // [row][k] bf16, row stride 32 (64B)
    __shared__ short Bs[128 * 32];
    const int t = threadIdx.x;
    const int lane = t & 63, wv = t >> 6;
    const int wm = wv >> 1, wn = wv & 1;           // 2x2 wave grid, 64x64 each
    const int row0 = blockIdx.y * 128, col0 = blockIdx.x * 128;
    const short* Ag = (const short*)A;
    const short* Bg = (const short*)Bm;
    const int srow = t >> 2;
    const int kch  = (t & 3) * 8;

    f32x4 acc[4][4] = {};

    for (int k0 = 0; k0 < KDIM; k0 += 32) {
        gload_lds16(Ag + (size_t)(row0 + srow) * KDIM + k0 + kch,      As + wv * 512);
        gload_lds16(Ag + (size_t)(row0 + 64 + srow) * KDIM + k0 + kch, As + 2048 + wv * 512);
        gload_lds16(Bg + (size_t)(col0 + srow) * KDIM + k0 + kch,      Bs + wv * 512);
        gload_lds16(Bg + (size_t)(col0 + 64 + srow) * KDIM + k0 + kch, Bs + 2048 + wv * 512);
        __syncthreads();

        const int rsel = lane & 15, ksel = (lane >> 4) * 8;
        short8 a[4], bfr[4];
#pragma unroll
        for (int mi = 0; mi < 4; ++mi)
            a[mi] = *(const short8*)&As[(wm * 64 + mi * 16 + rsel) * 32 + ksel];
#pragma unroll
        for (int ni = 0; ni < 4; ++ni)
            bfr[ni] = *(const short8*)&Bs[(wn * 64 + ni * 16 + rsel) * 32 + ksel];
#pragma unroll
        for (int mi = 0; mi < 4; ++mi)
#pragma unroll
            for (int ni = 0; ni < 4; ++ni)
                acc[mi][ni] = __builtin_amdgcn_mfma_f32_16x16x32_bf16(a[mi], bfr[ni], acc[mi][ni], 0, 0, 0);
        __syncthreads();
    }
    const int rbase = (lane >> 4) * 4, cbase = lane & 15;
#pragma unroll
    for (int mi = 0; mi < 4; ++mi) {
#pragma unroll
        for (int ni = 0; ni < 4; ++ni) {
            int r0 = row0 + wm * 64 + mi * 16 + rbase;
            int c  = col0 + wn * 64 + ni * 16 + cbase;
#pragma unroll
            for (int r = 0; r < 4; ++r)
                D[(size_t)(r0 + r) * NPIX + c] = f32_to_bf16(acc[mi][ni][r]);
        }
    }
}

// ---- K3: LDS-staged argmax + fused loss. One block per q (62x62 grid).
// The 9 taps of S[q,p] all live in 9 D rows (y = qpix + 64i + j). Stage those rows
// into LDS once (uint4, ~19 wide loads/thread) and take taps as ds_read_u16
// (stride-1 per lane -> 2-way bank aliasing = free). 2 col-strips keep LDS at
// 39.3 KB -> 4 blocks/CU. Reduce scratch overlays the stage buffer.
__global__ __launch_bounds__(256) void k_argmax_loss(
        const unsigned short* __restrict__ D,
        const float* __restrict__ ssP, const float* __restrict__ invP,
        const float* __restrict__ ssT, const float* __restrict__ invT,
        float* __restrict__ out) {
    const int qc = blockIdx.x, qr = blockIdx.y;
    const int qpix = qr * WW + qc;
    const int t = threadIdx.x;

    __shared__ __align__(16) unsigned char lds_raw[9 * SCOLS * 2];   // 39312 B
    unsigned short* stage = (unsigned short*)lds_raw;
    float* sS = (float*)lds_raw;                 // overlay (used after last tap read)
    int*   sI = (int*)(lds_raw + 1024);
    float* sL = (float*)(lds_raw + 2048);

    float best = -1e30f; int bidx = 0x7fffffff;

#pragma unroll
    for (int s = 0; s < 2; ++s) {
        const int B0 = s * 2048;
        if (s) __syncthreads();                  // all strip-0 reads done before restage
        // stage 9 rows x SCOLS cols as uint4 (8 bf16 each): 9*273 = 2457 chunks
        for (int c = t; c < 9 * 273; c += 256) {
            int k  = c / 273;
            int ch = c - k * 273;
            int col = B0 + ch * 8;
            if (col < NPIX) {
                int y = qpix + (k / 3) * 64 + (k - (k / 3) * 3);
                *(uint4*)&stage[k * SCOLS + ch * 8] =
                    *(const uint4*)(D + (size_t)y * NPIX + col);
            }
        }
        __syncthreads();
        const int ps = s ? 1984 : 0, pe = s ? NPATCH : 1984;   // pr<32 | pr>=32
        for (int p = ps + t; p < pe; p += 256) {
            int pr = p / OH, pc = p - pr * OH;
            int x = pr * 64 + pc - B0;
            float sv = 0.f;
#pragma unroll
            for (int k = 0; k < 9; ++k) {
                const int cs = (k / 3) * 64 + (k % 3);
                sv += bf16_to_f32(stage[k * SCOLS + x + cs]);
            }
            if (sv > best) { best = sv; bidx = p; }   // increasing p => first-max kept
        }
    }
    __syncthreads();                             // last LDS tap read done; overlay safe
    sS[t] = best; sI[t] = bidx;
    __syncthreads();
    for (int stride = 128; stride > 0; stride >>= 1) {
        if (t < stride) {
            float so = sS[t + stride]; int io = sI[t + stride];
            if (so > sS[t] || (so == sS[t] && io < sI[t])) { sS[t] = so; sI[t] = io; }
        }
        __syncthreads();
    }
    const int m = sI[0];
    const int mr = m / OH, mc = m - mr * OH;
    const int mpix = mr * WW + mc;
    if (t < 9) {                                 // parallel loss taps (no serial chain)
        int i = t / 3, j = t - i * 3;
        int off = i * WW + j;
        int y = qpix + off, x = mpix + off;
        float Dv = bf16_to_f32(D[(size_t)y * NPIX + x]);
        float nP = ssP[y] * invP[y];             // = ||p_y||
        float nT = ssT[x] * invT[x];
        sL[t] = ssP[y] + ssT[x] - 2.f * Dv * nP * nT;
    }
    __syncthreads();
    if (t == 0) {
        float acc = 0.f;
#pragma unroll
        for (int k = 0; k < 9; ++k) acc += sL[k];
        atomicAdd(out, acc * (1.f / 35426304.f));   // / (4*3844*2304)
    }
}

// ---------------------------------- launch ----------------------------------
extern "C" void kernel_launch(void* const* d_in, const int* in_sizes, int n_in,
                              void* d_out, int out_size, void* d_ws, size_t ws_size,
                              hipStream_t stream) {
    const float* pred = (const float*)d_in[0];
    const float* tgt  = (const float*)d_in[1];
    char* ws = (char*)d_ws;
    // ws layout (bytes): D(bf16) 32MB | Xn 8MB | Tn 8MB | ssP/invP/ssT/invT 64KB ea
    unsigned short* Dws  = (unsigned short*)(ws);
    __hip_bfloat16* Xn   = (__hip_bfloat16*)(ws + 33554432);
    __hip_bfloat16* Tn   = (__hip_bfloat16*)(ws + 41943040);
    float*          ssP  = (float*)(ws + 50331648);
    float*          invP = (float*)(ws + 50397184);
    float*          ssT  = (float*)(ws + 50462720);
    float*          invT = (float*)(ws + 50528256);

    hipMemsetAsync(d_out, 0, sizeof(float), stream);
    k_prep<<<dim3(64, 8), 256, 0, stream>>>(pred, tgt, Xn, Tn, ssP, invP, ssT, invT);
    for (int b = 0; b < NB; ++b) {
        const __hip_bfloat16* Ab = Xn + (size_t)b * NPIX * CH;
        const __hip_bfloat16* Bb = Tn + (size_t)b * NPIX * CH;
        k_gemm<<<dim3(32, 32), 256, 0, stream>>>(Ab, Bb, Dws);
        k_argmax_loss<<<dim3(62, 62), 256, 0, stream>>>(Dws,
                                       ssP + b * NPIX, invP + b * NPIX,
                                       ssT + b * NPIX, invT + b * NPIX,
                                       (float*)d_out);
    }
}

// Round 5
// 394.679 us; speedup vs baseline: 1.1411x; 1.1411x over previous
//
#include <hip/hip_runtime.h>
#include <hip/hip_bf16.h>

#define NB 4
#define CH 256
#define HH 64
#define WW 64
#define NPIX 4096      // HH*WW
#define OH 62
#define NPATCH 3844    // 62*62
#define KDIM 256       // == CH
#define EPSN 1e-12f
#define GCOLS 2184     // per-strip staged G columns (2048 + 130 halo, mult of 8)

typedef __attribute__((ext_vector_type(8))) short short8;
typedef __attribute__((ext_vector_type(4))) float f32x4;

__device__ __forceinline__ float bf16_to_f32(unsigned short u) {
    return __uint_as_float((unsigned)u << 16);
}
__device__ __forceinline__ unsigned short f32_to_bf16(float f) {
    __hip_bfloat16 h = __float2bfloat16(f);
    return *(unsigned short*)&h;
}

// ---- K1 (fused prep): read inputs ONCE; per-pixel ss + inv-norm; normalized bf16
// ---- transpose (C,pix)->(pix,C).  Grid (64 pixtiles, 8 = b*2+which), 256 thr.
__global__ __launch_bounds__(256) void k_prep(const float* __restrict__ pred,
                                              const float* __restrict__ tgt,
                                              __hip_bfloat16* __restrict__ Xn,
                                              __hip_bfloat16* __restrict__ Tn,
                                              float* __restrict__ ssP, float* __restrict__ invP,
                                              float* __restrict__ ssT, float* __restrict__ invT) {
    const int bz = blockIdx.y;            // 0..7
    const int b = bz >> 1, which = bz & 1;
    const float* src = (which ? tgt : pred) + (size_t)b * CH * NPIX;
    unsigned short* dst = (unsigned short*)((which ? Tn : Xn) + (size_t)b * NPIX * CH);
    float* ss_g  = (which ? ssT  : ssP)  + b * NPIX;
    float* inv_g = (which ? invT : invP) + b * NPIX;
    const int pix0 = blockIdx.x * 64;
    const int t = threadIdx.x, lane = t & 63, wv = t >> 6;

    __shared__ unsigned short stage[CH][65];   // bf16, +1 pad
    __shared__ float partial[4][64];
    __shared__ float inv_s[64];

    float ssacc = 0.f;
#pragma unroll 8
    for (int cc = 0; cc < 64; ++cc) {
        int c = wv * 64 + cc;
        float v = src[(size_t)c * NPIX + pix0 + lane];
        ssacc += v * v;
        stage[c][lane] = f32_to_bf16(v);
    }
    partial[wv][lane] = ssacc;
    __syncthreads();
    if (t < 64) {
        float ss = partial[0][t] + partial[1][t] + partial[2][t] + partial[3][t];
        float inv = 1.f / fmaxf(sqrtf(ss), EPSN);
        ss_g[pix0 + t] = ss;
        inv_g[pix0 + t] = inv;
        inv_s[t] = inv;
    }
    __syncthreads();
    for (int p = wv; p < 64; p += 4) {
        float iv = inv_s[p];
#pragma unroll
        for (int cb = 0; cb < 4; ++cb) {
            int c = cb * 64 + lane;
            float v = bf16_to_f32(stage[c][p]) * iv;
            dst[(size_t)(pix0 + p) * CH + c] = f32_to_bf16(v);
        }
    }
}

// ------- K2: D = Xn * Tn^T (4096x4096, K=256, bf16 MFMA, bf16 OUTPUT), z = batch -------
__device__ __forceinline__ void gload_lds16(const void* g, void* l) {
    __builtin_amdgcn_global_load_lds(
        (const __attribute__((address_space(1))) void*)g,
        (__attribute__((address_space(3))) void*)l, 16, 0, 0);
}

__global__ __launch_bounds__(256) void k_gemm(const __hip_bfloat16* __restrict__ A,
                                              const __hip_bfloat16* __restrict__ Bm,
                                              unsigned short* __restrict__ Dout) {
    __shared__ short As[128 * 32];   // [row][k] bf16, row stride 32 (64B)
    __shared__ short Bs[128 * 32];
    const int z = blockIdx.z;
    const int t = threadIdx.x;
    const int lane = t & 63, wv = t >> 6;
    const int wm = wv >> 1, wn = wv & 1;           // 2x2 wave grid, 64x64 each
    const int row0 = blockIdx.y * 128, col0 = blockIdx.x * 128;
    const short* Ag = (const short*)A + (size_t)z * NPIX * CH;
    const short* Bg = (const short*)Bm + (size_t)z * NPIX * CH;
    unsigned short* D = Dout + (size_t)z * NPIX * NPIX;
    const int srow = t >> 2;
    const int kch  = (t & 3) * 8;

    f32x4 acc[4][4] = {};

    for (int k0 = 0; k0 < KDIM; k0 += 32) {
        gload_lds16(Ag + (size_t)(row0 + srow) * KDIM + k0 + kch,      As + wv * 512);
        gload_lds16(Ag + (size_t)(row0 + 64 + srow) * KDIM + k0 + kch, As + 2048 + wv * 512);
        gload_lds16(Bg + (size_t)(col0 + srow) * KDIM + k0 + kch,      Bs + wv * 512);
        gload_lds16(Bg + (size_t)(col0 + 64 + srow) * KDIM + k0 + kch, Bs + 2048 + wv * 512);
        __syncthreads();

        const int rsel = lane & 15, ksel = (lane >> 4) * 8;
        short8 a[4], bfr[4];
#pragma unroll
        for (int mi = 0; mi < 4; ++mi)
            a[mi] = *(const short8*)&As[(wm * 64 + mi * 16 + rsel) * 32 + ksel];
#pragma unroll
        for (int ni = 0; ni < 4; ++ni)
            bfr[ni] = *(const short8*)&Bs[(wn * 64 + ni * 16 + rsel) * 32 + ksel];
#pragma unroll
        for (int mi = 0; mi < 4; ++mi)
#pragma unroll
            for (int ni = 0; ni < 4; ++ni)
                acc[mi][ni] = __builtin_amdgcn_mfma_f32_16x16x32_bf16(a[mi], bfr[ni], acc[mi][ni], 0, 0, 0);
        __syncthreads();
    }
    const int rbase = (lane >> 4) * 4, cbase = lane & 15;
#pragma unroll
    for (int mi = 0; mi < 4; ++mi) {
#pragma unroll
        for (int ni = 0; ni < 4; ++ni) {
            int r0 = row0 + wm * 64 + mi * 16 + rbase;
            int c  = col0 + wn * 64 + ni * 16 + cbase;
#pragma unroll
            for (int r = 0; r < 4; ++r)
                D[(size_t)(r0 + r) * NPIX + c] = f32_to_bf16(acc[mi][ni][r]);
        }
    }
}

// ---- K3: separable argmax + fused loss. One block per (q, batch-in-pair).
// S[q,p] = sum_i G_i[ppix+64i] with G_i[x] = sum_j D[qpix+64i+j, x+j] (j=0..2).
// Stage G_i as f32 in LDS (wide uint4 global reads, ds_write_b128), tap-sum via
// aligned ds_read_b128. Two pr-strips keep LDS at 26.2 KB -> 6 blocks/CU.
__global__ __launch_bounds__(256) void k_argmax_loss(
        const unsigned short* __restrict__ Dbase,
        const float* __restrict__ ssPb, const float* __restrict__ invPb,
        const float* __restrict__ ssTb, const float* __restrict__ invTb,
        float* __restrict__ out) {
    const int z = blockIdx.z;
    const unsigned short* D = Dbase + (size_t)z * NPIX * NPIX;
    const float* ssP  = ssPb  + z * NPIX;
    const float* invP = invPb + z * NPIX;
    const float* ssT  = ssTb  + z * NPIX;
    const float* invT = invTb + z * NPIX;

    const int qc = blockIdx.x, qr = blockIdx.y;
    const int qpix = qr * WW + qc;
    const int t = threadIdx.x;

    __shared__ __align__(16) float G[3][GCOLS];     // 26208 B
    float* sS = &G[0][0];                           // overlays (after last G read)
    int*   sI = (int*)&G[0][256];
    float* sL = &G[0][512];

    float best = -1e30f; int bidx = 0;

#pragma unroll
    for (int s = 0; s < 2; ++s) {
        const int B0 = s * 2048;
        if (s) __syncthreads();                     // strip-0 reads done before restage
        // ---- stage G: 3 arrays x 273 chunks of 8 ----
        for (int task = t; task < 3 * 273; task += 256) {
            int i = task / 273, ch = task - i * 273;
            int col = B0 + ch * 8;                  // global D col of x=8ch
            if (col >= NPIX) continue;              // fully OOB chunk: never read
            int y = qpix + i * 64;
            float v[3][10];
            if (col + 10 <= NPIX) {
#pragma unroll
                for (int r = 0; r < 3; ++r) {
                    const unsigned short* rp = D + (size_t)(y + r) * NPIX + col;
                    uint4 u = *(const uint4*)rp;
                    unsigned ux = *(const unsigned*)(rp + 8);
                    v[r][0] = bf16_to_f32((unsigned short)(u.x));
                    v[r][1] = bf16_to_f32((unsigned short)(u.x >> 16));
                    v[r][2] = bf16_to_f32((unsigned short)(u.y));
                    v[r][3] = bf16_to_f32((unsigned short)(u.y >> 16));
                    v[r][4] = bf16_to_f32((unsigned short)(u.z));
                    v[r][5] = bf16_to_f32((unsigned short)(u.z >> 16));
                    v[r][6] = bf16_to_f32((unsigned short)(u.w));
                    v[r][7] = bf16_to_f32((unsigned short)(u.w >> 16));
                    v[r][8] = bf16_to_f32((unsigned short)(ux));
                    v[r][9] = bf16_to_f32((unsigned short)(ux >> 16));
                }
            } else {                                // partial chunk (rare)
#pragma unroll
                for (int r = 0; r < 3; ++r)
                    for (int e = 0; e < 10; ++e)
                        v[r][e] = (col + e < NPIX)
                                ? bf16_to_f32(D[(size_t)(y + r) * NPIX + col + e]) : 0.f;
            }
            float g[8];
#pragma unroll
            for (int e = 0; e < 8; ++e) g[e] = v[0][e] + v[1][e + 1] + v[2][e + 2];
            *(f32x4*)&G[i][ch * 8]     = *(f32x4*)&g[0];
            *(f32x4*)&G[i][ch * 8 + 4] = *(f32x4*)&g[4];
        }
        __syncthreads();
        // ---- tap-sum: 1 chunk of 8 pc per thread ----
        const int ntask = s ? 240 : 256;            // strip1: 30 pr x 8 chunks
        if (t < ntask) {
            int pr_l = t >> 3, j = t & 7;
            int pr = s * 32 + pr_l;
            int x = pr_l * 64 + j * 8;              // strip-local, mult of 8
            f32x4 a0 = *(const f32x4*)&G[0][x];
            f32x4 a1 = *(const f32x4*)&G[0][x + 4];
            f32x4 b0 = *(const f32x4*)&G[1][x + 64];
            f32x4 b1 = *(const f32x4*)&G[1][x + 68];
            f32x4 c0 = *(const f32x4*)&G[2][x + 128];
            f32x4 c1 = *(const f32x4*)&G[2][x + 132];
            f32x4 s0 = a0 + b0 + c0, s1 = a1 + b1 + c1;
            int pc0 = j * 8;
            int pbase = pr * OH + pc0;
            float sv[8] = {s0.x, s0.y, s0.z, s0.w, s1.x, s1.y, s1.z, s1.w};
#pragma unroll
            for (int e = 0; e < 8; ++e) {
                if (pc0 + e < OH && sv[e] > best) { best = sv[e]; bidx = pbase + e; }
            }
        }
    }
    __syncthreads();                                // last G reads done; overlay safe
    sS[t] = best; sI[t] = bidx;
    __syncthreads();
    for (int stride = 128; stride > 0; stride >>= 1) {
        if (t < stride) {
            float so = sS[t + stride]; int io = sI[t + stride];
            if (so > sS[t] || (so == sS[t] && io < sI[t])) { sS[t] = so; sI[t] = io; }
        }
        __syncthreads();
    }
    const int m = sI[0];
    const int mr = m / OH, mc = m - mr * OH;
    const int mpix = mr * WW + mc;
    if (t < 9) {                                    // parallel loss taps
        int i = t / 3, j = t - i * 3;
        int off = i * WW + j;
        int y = qpix + off, x = mpix + off;
        float Dv = bf16_to_f32(D[(size_t)y * NPIX + x]);
        float nP = ssP[y] * invP[y];                // = ||p_y||
        float nT = ssT[x] * invT[x];
        sL[t] = ssP[y] + ssT[x] - 2.f * Dv * nP * nT;
    }
    __syncthreads();
    if (t == 0) {
        float acc = 0.f;
#pragma unroll
        for (int k = 0; k < 9; ++k) acc += sL[k];
        atomicAdd(out, acc * (1.f / 35426304.f));   // / (4*3844*2304)
    }
}

// ---------------------------------- launch ----------------------------------
extern "C" void kernel_launch(void* const* d_in, const int* in_sizes, int n_in,
                              void* d_out, int out_size, void* d_ws, size_t ws_size,
                              hipStream_t stream) {
    const float* pred = (const float*)d_in[0];
    const float* tgt  = (const float*)d_in[1];
    char* ws = (char*)d_ws;
    // ws layout (bytes): D(bf16, 2 batches) 64MB | Xn 8MB | Tn 8MB | norms 4x64KB
    unsigned short* Dws  = (unsigned short*)(ws);
    __hip_bfloat16* Xn   = (__hip_bfloat16*)(ws + 67108864);
    __hip_bfloat16* Tn   = (__hip_bfloat16*)(ws + 75497472);
    float*          ssP  = (float*)(ws + 83886080);
    float*          invP = (float*)(ws + 83951616);
    float*          ssT  = (float*)(ws + 84017152);
    float*          invT = (float*)(ws + 84082688);

    hipMemsetAsync(d_out, 0, sizeof(float), stream);
    k_prep<<<dim3(64, 8), 256, 0, stream>>>(pred, tgt, Xn, Tn, ssP, invP, ssT, invT);
    for (int pair = 0; pair < 2; ++pair) {
        int b0 = pair * 2;
        k_gemm<<<dim3(32, 32, 2), 256, 0, stream>>>(Xn + (size_t)b0 * NPIX * CH,
                                                    Tn + (size_t)b0 * NPIX * CH, Dws);
        k_argmax_loss<<<dim3(62, 62, 2), 256, 0, stream>>>(Dws,
                                       ssP + b0 * NPIX, invP + b0 * NPIX,
                                       ssT + b0 * NPIX, invT + b0 * NPIX,
                                       (float*)d_out);
    }
}

// Round 6
// 229.157 us; speedup vs baseline: 1.9654x; 1.7223x over previous
//
#include <hip/hip_runtime.h>
#include <hip/hip_bf16.h>

#define NB 4
#define CH 256
#define HH 64
#define WW 64
#define NPIX 4096      // HH*WW
#define OH 62
#define NPATCH 3844    // 62*62
#define KDIM 256       // == CH
#define EPSN 1e-12f
#define VSTRIDE 65     // odd stride: lane=row reads are conflict-free

typedef __attribute__((ext_vector_type(8))) short short8;
typedef __attribute__((ext_vector_type(4))) float f32x4;

__device__ __forceinline__ float bf16_to_f32(unsigned short u) {
    return __uint_as_float((unsigned)u << 16);
}
__device__ __forceinline__ unsigned short f32_to_bf16(float f) {
    __hip_bfloat16 h = __float2bfloat16(f);
    return *(unsigned short*)&h;
}

// ---- K1 (fused prep): read inputs ONCE; per-pixel ss + inv-norm; normalized bf16
// ---- transpose (C,pix)->(pix,C).  Grid (64 pixtiles, 8 = b*2+which), 256 thr.
__global__ __launch_bounds__(256) void k_prep(const float* __restrict__ pred,
                                              const float* __restrict__ tgt,
                                              __hip_bfloat16* __restrict__ Xn,
                                              __hip_bfloat16* __restrict__ Tn,
                                              float* __restrict__ ssP, float* __restrict__ invP,
                                              float* __restrict__ ssT, float* __restrict__ invT) {
    const int bz = blockIdx.y;            // 0..7
    const int b = bz >> 1, which = bz & 1;
    const float* src = (which ? tgt : pred) + (size_t)b * CH * NPIX;
    unsigned short* dst = (unsigned short*)((which ? Tn : Xn) + (size_t)b * NPIX * CH);
    float* ss_g  = (which ? ssT  : ssP)  + b * NPIX;
    float* inv_g = (which ? invT : invP) + b * NPIX;
    const int pix0 = blockIdx.x * 64;
    const int t = threadIdx.x, lane = t & 63, wv = t >> 6;

    __shared__ unsigned short stage[CH][65];   // bf16, +1 pad
    __shared__ float partial[4][64];
    __shared__ float inv_s[64];

    float ssacc = 0.f;
#pragma unroll 8
    for (int cc = 0; cc < 64; ++cc) {
        int c = wv * 64 + cc;
        float v = src[(size_t)c * NPIX + pix0 + lane];
        ssacc += v * v;
        stage[c][lane] = f32_to_bf16(v);
    }
    partial[wv][lane] = ssacc;
    __syncthreads();
    if (t < 64) {
        float ss = partial[0][t] + partial[1][t] + partial[2][t] + partial[3][t];
        float inv = 1.f / fmaxf(sqrtf(ss), EPSN);
        ss_g[pix0 + t] = ss;
        inv_g[pix0 + t] = inv;
        inv_s[t] = inv;
    }
    __syncthreads();
    for (int p = wv; p < 64; p += 4) {
        float iv = inv_s[p];
#pragma unroll
        for (int cb = 0; cb < 4; ++cb) {
            int c = cb * 64 + lane;
            float v = bf16_to_f32(stage[c][p]) * iv;
            dst[(size_t)(pix0 + p) * CH + c] = f32_to_bf16(v);
        }
    }
}

// ------- K2: D = Xn * Tn^T (4096x4096, K=256, bf16 MFMA, bf16 OUTPUT), z = batch -------
__device__ __forceinline__ void gload_lds16(const void* g, void* l) {
    __builtin_amdgcn_global_load_lds(
        (const __attribute__((address_space(1))) void*)g,
        (__attribute__((address_space(3))) void*)l, 16, 0, 0);
}

__global__ __launch_bounds__(256) void k_gemm(const __hip_bfloat16* __restrict__ A,
                                              const __hip_bfloat16* __restrict__ Bm,
                                              unsigned short* __restrict__ Dout) {
    __shared__ short As[128 * 32];   // [row][k] bf16, row stride 32 (64B)
    __shared__ short Bs[128 * 32];
    const int z = blockIdx.z;
    const int t = threadIdx.x;
    const int lane = t & 63, wv = t >> 6;
    const int wm = wv >> 1, wn = wv & 1;           // 2x2 wave grid, 64x64 each
    const int row0 = blockIdx.y * 128, col0 = blockIdx.x * 128;
    const short* Ag = (const short*)A + (size_t)z * NPIX * CH;
    const short* Bg = (const short*)Bm + (size_t)z * NPIX * CH;
    unsigned short* D = Dout + (size_t)z * NPIX * NPIX;
    const int srow = t >> 2;
    const int kch  = (t & 3) * 8;

    f32x4 acc[4][4] = {};

    for (int k0 = 0; k0 < KDIM; k0 += 32) {
        gload_lds16(Ag + (size_t)(row0 + srow) * KDIM + k0 + kch,      As + wv * 512);
        gload_lds16(Ag + (size_t)(row0 + 64 + srow) * KDIM + k0 + kch, As + 2048 + wv * 512);
        gload_lds16(Bg + (size_t)(col0 + srow) * KDIM + k0 + kch,      Bs + wv * 512);
        gload_lds16(Bg + (size_t)(col0 + 64 + srow) * KDIM + k0 + kch, Bs + 2048 + wv * 512);
        __syncthreads();

        const int rsel = lane & 15, ksel = (lane >> 4) * 8;
        short8 a[4], bfr[4];
#pragma unroll
        for (int mi = 0; mi < 4; ++mi)
            a[mi] = *(const short8*)&As[(wm * 64 + mi * 16 + rsel) * 32 + ksel];
#pragma unroll
        for (int ni = 0; ni < 4; ++ni)
            bfr[ni] = *(const short8*)&Bs[(wn * 64 + ni * 16 + rsel) * 32 + ksel];
#pragma unroll
        for (int mi = 0; mi < 4; ++mi)
#pragma unroll
            for (int ni = 0; ni < 4; ++ni)
                acc[mi][ni] = __builtin_amdgcn_mfma_f32_16x16x32_bf16(a[mi], bfr[ni], acc[mi][ni], 0, 0, 0);
        __syncthreads();
    }
    const int rbase = (lane >> 4) * 4, cbase = lane & 15;
#pragma unroll
    for (int mi = 0; mi < 4; ++mi) {
#pragma unroll
        for (int ni = 0; ni < 4; ++ni) {
            int r0 = row0 + wm * 64 + mi * 16 + rbase;
            int c  = col0 + wn * 64 + ni * 16 + cbase;
#pragma unroll
            for (int r = 0; r < 4; ++r)
                D[(size_t)(r0 + r) * NPIX + c] = f32_to_bf16(acc[mi][ni][r]);
        }
    }
}

// ---- K3 (k_score): tile-pair scores. Block = (pr, qr, z). S-block(qr,pr)[qc,pc] =
// V[qc,pc]+V[qc+1,pc+1]+V[qc+2,pc+2],  V = sum_i Dtile(qr+i, pr+i)  (elementwise!).
// Only 3 x 8KB of D per block. V stored transposed f32 (odd stride 65 -> lane=qc
// reads conflict-free). Fold over pr-blocks via u64 atomicMax keys (exact
// value-desc + first-index semantics: key = monotone(f32)<<12 | (63-pr)<<6|(63-pc)).
__global__ __launch_bounds__(256) void k_score(const unsigned short* __restrict__ Dbase,
                                               unsigned long long* __restrict__ keys) {
    const int z = blockIdx.z;
    const unsigned short* D = Dbase + (size_t)z * NPIX * NPIX;
    const int pr = blockIdx.x, qr = blockIdx.y;
    const int t = threadIdx.x;

    __shared__ float VT[64 * VSTRIDE + 8];         // 16.7 KB, transposed: VT[b*65+a]

    // ---- stage: thread t covers row a = t>>2, cols b0..b0+16 (two uint4 per tile)
    const int a  = t >> 2;
    const int b0 = (t & 3) * 16;
    float v[16];
#pragma unroll
    for (int e = 0; e < 16; ++e) v[e] = 0.f;
#pragma unroll
    for (int i = 0; i < 3; ++i) {
        const unsigned short* rp =
            D + (size_t)((qr + i) * 64 + a) * NPIX + (pr + i) * 64 + b0;
        uint4 u0 = *(const uint4*)rp;
        uint4 u1 = *(const uint4*)(rp + 8);
        const unsigned* uw = (const unsigned*)&u0;
#pragma unroll
        for (int w = 0; w < 4; ++w) {
            v[2 * w]     += bf16_to_f32((unsigned short)uw[w]);
            v[2 * w + 1] += bf16_to_f32((unsigned short)(uw[w] >> 16));
        }
        const unsigned* uw1 = (const unsigned*)&u1;
#pragma unroll
        for (int w = 0; w < 4; ++w) {
            v[8 + 2 * w]     += bf16_to_f32((unsigned short)uw1[w]);
            v[8 + 2 * w + 1] += bf16_to_f32((unsigned short)(uw1[w] >> 16));
        }
    }
#pragma unroll
    for (int e = 0; e < 16; ++e)
        VT[(b0 + e) * VSTRIDE + a] = v[e];         // 2-way bank alias = free
    __syncthreads();

    // ---- score: wave g handles pc in [16g, 16g+16); lane = qc
    const int g = t >> 6, qc = t & 63;
    float best = -1e30f; int bpc = 0;
    const int kmax = (g == 3) ? 14 : 16;           // pc < 62 (wave-uniform trip count)
    for (int k = 0; k < kmax; ++k) {
        int pc = g * 16 + k;
        float s = VT[pc * VSTRIDE + qc]
                + VT[(pc + 1) * VSTRIDE + qc + 1]
                + VT[(pc + 2) * VSTRIDE + qc + 2];
        if (s > best) { best = s; bpc = pc; }      // ascending pc => first-max kept
    }
    if (qc < OH) {
        unsigned u = __float_as_uint(best);
        u = (best >= 0.f) ? (u | 0x80000000u) : ~u;
        unsigned long long key = ((unsigned long long)u << 12)
                               | (unsigned)((63 - pr) << 6) | (unsigned)(63 - bpc);
        atomicMax(&keys[(size_t)z * NPATCH + qr * OH + qc], key);
    }
}

// -------- K4 (k_loss): decode keys -> match; loss via norm expansion --------
__global__ void k_loss(const unsigned short* __restrict__ Dbase,
                       const unsigned long long* __restrict__ keys,
                       const float* __restrict__ ssPb, const float* __restrict__ invPb,
                       const float* __restrict__ ssTb, const float* __restrict__ invTb,
                       float* __restrict__ out) {
    const int z = blockIdx.y;
    const unsigned short* D = Dbase + (size_t)z * NPIX * NPIX;
    const float* ssP  = ssPb  + z * NPIX;
    const float* invP = invPb + z * NPIX;
    const float* ssT  = ssTb  + z * NPIX;
    const float* invT = invTb + z * NPIX;
    int q = blockIdx.x * 256 + threadIdx.x;
    float acc = 0.f;
    if (q < NPATCH) {
        int qr = q / OH, qc = q - qr * OH;
        int qpix = qr * WW + qc;
        unsigned long long key = keys[(size_t)z * NPATCH + q];
        int mpr = 63 - (int)((key >> 6) & 63);
        int mpc = 63 - (int)(key & 63);
        int mpix = mpr * WW + mpc;
#pragma unroll
        for (int i = 0; i < 3; ++i)
#pragma unroll
            for (int j = 0; j < 3; ++j) {
                int off = i * WW + j;
                int y = qpix + off, x = mpix + off;
                float Dv = bf16_to_f32(D[(size_t)y * NPIX + x]);
                float nP = ssP[y] * invP[y];       // = ||p_y||
                float nT = ssT[x] * invT[x];
                acc += ssP[y] + ssT[x] - 2.f * Dv * nP * nT;
            }
    }
#pragma unroll
    for (int s = 32; s > 0; s >>= 1) acc += __shfl_down(acc, s, 64);
    if ((threadIdx.x & 63) == 0)
        atomicAdd(out, acc * (1.f / 35426304.f));  // / (4*3844*2304)
}

// ---------------------------------- launch ----------------------------------
extern "C" void kernel_launch(void* const* d_in, const int* in_sizes, int n_in,
                              void* d_out, int out_size, void* d_ws, size_t ws_size,
                              hipStream_t stream) {
    const float* pred = (const float*)d_in[0];
    const float* tgt  = (const float*)d_in[1];
    char* ws = (char*)d_ws;
    // ws layout (bytes): D(bf16, 2 batches) 64MB | Xn 8MB | Tn 8MB | norms 4x64KB | keys 61.5KB
    unsigned short*     Dws  = (unsigned short*)(ws);
    __hip_bfloat16*     Xn   = (__hip_bfloat16*)(ws + 67108864);
    __hip_bfloat16*     Tn   = (__hip_bfloat16*)(ws + 75497472);
    float*              ssP  = (float*)(ws + 83886080);
    float*              invP = (float*)(ws + 83951616);
    float*              ssT  = (float*)(ws + 84017152);
    float*              invT = (float*)(ws + 84082688);
    unsigned long long* keys = (unsigned long long*)(ws + 84148224);

    hipMemsetAsync(d_out, 0, sizeof(float), stream);
    k_prep<<<dim3(64, 8), 256, 0, stream>>>(pred, tgt, Xn, Tn, ssP, invP, ssT, invT);
    for (int pair = 0; pair < 2; ++pair) {
        int b0 = pair * 2;
        k_gemm<<<dim3(32, 32, 2), 256, 0, stream>>>(Xn + (size_t)b0 * NPIX * CH,
                                                    Tn + (size_t)b0 * NPIX * CH, Dws);
        hipMemsetAsync(keys, 0, 2 * NPATCH * sizeof(unsigned long long), stream);
        k_score<<<dim3(62, 62, 2), 256, 0, stream>>>(Dws, keys);
        k_loss<<<dim3(16, 2), 256, 0, stream>>>(Dws, keys,
                                       ssP + b0 * NPIX, invP + b0 * NPIX,
                                       ssT + b0 * NPIX, invT + b0 * NPIX,
                                       (float*)d_out);
    }
}

// Round 7
// 204.616 us; speedup vs baseline: 2.2011x; 1.1199x over previous
//
#include <hip/hip_runtime.h>
#include <hip/hip_bf16.h>

#define NB 4
#define CH 256
#define HH 64
#define WW 64
#define NPIX 4096      // HH*WW
#define OH 62
#define NPATCH 3844    // 62*62
#define KDIM 256       // == CH
#define EPSN 1e-12f
#define VSTRIDE 65     // odd stride: lane=row reads are conflict-free

typedef __attribute__((ext_vector_type(8))) short short8;
typedef __attribute__((ext_vector_type(4))) float f32x4;

__device__ __forceinline__ float bf16_to_f32(unsigned short u) {
    return __uint_as_float((unsigned)u << 16);
}
__device__ __forceinline__ unsigned short f32_to_bf16(float f) {
    __hip_bfloat16 h = __float2bfloat16(f);
    return *(unsigned short*)&h;
}

// ---- K1 (fused prep): read inputs ONCE; per-pixel ss + inv-norm; normalized bf16
// ---- transpose (C,pix)->(pix,C). Also zero-inits d_out + keys (kills 3 memset
// ---- dispatches; stream order makes them visible to k_score/k_loss).
__global__ __launch_bounds__(256) void k_prep(const float* __restrict__ pred,
                                              const float* __restrict__ tgt,
                                              __hip_bfloat16* __restrict__ Xn,
                                              __hip_bfloat16* __restrict__ Tn,
                                              float* __restrict__ ssP, float* __restrict__ invP,
                                              float* __restrict__ ssT, float* __restrict__ invT,
                                              unsigned long long* __restrict__ keys,
                                              float* __restrict__ out) {
    const int bz = blockIdx.y;            // 0..7
    const int b = bz >> 1, which = bz & 1;
    const float* src = (which ? tgt : pred) + (size_t)b * CH * NPIX;
    unsigned short* dst = (unsigned short*)((which ? Tn : Xn) + (size_t)b * NPIX * CH);
    float* ss_g  = (which ? ssT  : ssP)  + b * NPIX;
    float* inv_g = (which ? invT : invP) + b * NPIX;
    const int pix0 = blockIdx.x * 64;
    const int t = threadIdx.x, lane = t & 63, wv = t >> 6;

    // init side-duties (512 blocks x 256 thr = 131072 >= 4*NPATCH)
    int gid = (bz * 64 + blockIdx.x) * 256 + t;
    if (gid < NB * NPATCH) keys[gid] = 0ull;
    if (gid == 0) out[0] = 0.f;

    __shared__ unsigned short stage[CH][65];   // bf16, +1 pad
    __shared__ float partial[4][64];
    __shared__ float inv_s[64];

    float ssacc = 0.f;
#pragma unroll 8
    for (int cc = 0; cc < 64; ++cc) {
        int c = wv * 64 + cc;
        float v = src[(size_t)c * NPIX + pix0 + lane];
        ssacc += v * v;
        stage[c][lane] = f32_to_bf16(v);
    }
    partial[wv][lane] = ssacc;
    __syncthreads();
    if (t < 64) {
        float ss = partial[0][t] + partial[1][t] + partial[2][t] + partial[3][t];
        float inv = 1.f / fmaxf(sqrtf(ss), EPSN);
        ss_g[pix0 + t] = ss;
        inv_g[pix0 + t] = inv;
        inv_s[t] = inv;
    }
    __syncthreads();
    for (int p = wv; p < 64; p += 4) {
        float iv = inv_s[p];
#pragma unroll
        for (int cb = 0; cb < 4; ++cb) {
            int c = cb * 64 + lane;
            float v = bf16_to_f32(stage[c][p]) * iv;
            dst[(size_t)(pix0 + p) * CH + c] = f32_to_bf16(v);
        }
    }
}

// ------- K2: D = Xn * Tn^T (4096x4096, K=256, bf16 MFMA, bf16 OUTPUT), z = batch -------
__device__ __forceinline__ void gload_lds16(const void* g, void* l) {
    __builtin_amdgcn_global_load_lds(
        (const __attribute__((address_space(1))) void*)g,
        (__attribute__((address_space(3))) void*)l, 16, 0, 0);
}

__global__ __launch_bounds__(256) void k_gemm(const __hip_bfloat16* __restrict__ A,
                                              const __hip_bfloat16* __restrict__ Bm,
                                              unsigned short* __restrict__ Dout) {
    __shared__ short As[128 * 32];   // [row][k] bf16, row stride 32 (64B)
    __shared__ short Bs[128 * 32];
    const int z = blockIdx.z;
    const int t = threadIdx.x;
    const int lane = t & 63, wv = t >> 6;
    const int wm = wv >> 1, wn = wv & 1;           // 2x2 wave grid, 64x64 each
    const int row0 = blockIdx.y * 128, col0 = blockIdx.x * 128;
    const short* Ag = (const short*)A + (size_t)z * NPIX * CH;
    const short* Bg = (const short*)Bm + (size_t)z * NPIX * CH;
    unsigned short* D = Dout + (size_t)z * NPIX * NPIX;
    const int srow = t >> 2;
    const int kch  = (t & 3) * 8;

    f32x4 acc[4][4] = {};

    for (int k0 = 0; k0 < KDIM; k0 += 32) {
        gload_lds16(Ag + (size_t)(row0 + srow) * KDIM + k0 + kch,      As + wv * 512);
        gload_lds16(Ag + (size_t)(row0 + 64 + srow) * KDIM + k0 + kch, As + 2048 + wv * 512);
        gload_lds16(Bg + (size_t)(col0 + srow) * KDIM + k0 + kch,      Bs + wv * 512);
        gload_lds16(Bg + (size_t)(col0 + 64 + srow) * KDIM + k0 + kch, Bs + 2048 + wv * 512);
        __syncthreads();

        const int rsel = lane & 15, ksel = (lane >> 4) * 8;
        short8 a[4], bfr[4];
#pragma unroll
        for (int mi = 0; mi < 4; ++mi)
            a[mi] = *(const short8*)&As[(wm * 64 + mi * 16 + rsel) * 32 + ksel];
#pragma unroll
        for (int ni = 0; ni < 4; ++ni)
            bfr[ni] = *(const short8*)&Bs[(wn * 64 + ni * 16 + rsel) * 32 + ksel];
#pragma unroll
        for (int mi = 0; mi < 4; ++mi)
#pragma unroll
            for (int ni = 0; ni < 4; ++ni)
                acc[mi][ni] = __builtin_amdgcn_mfma_f32_16x16x32_bf16(a[mi], bfr[ni], acc[mi][ni], 0, 0, 0);
        __syncthreads();
    }
    const int rbase = (lane >> 4) * 4, cbase = lane & 15;
#pragma unroll
    for (int mi = 0; mi < 4; ++mi) {
#pragma unroll
        for (int ni = 0; ni < 4; ++ni) {
            int r0 = row0 + wm * 64 + mi * 16 + rbase;
            int c  = col0 + wn * 64 + ni * 16 + cbase;
#pragma unroll
            for (int r = 0; r < 4; ++r)
                D[(size_t)(r0 + r) * NPIX + c] = f32_to_bf16(acc[mi][ni][r]);
        }
    }
}

// ---- K3 (k_score): tile-pair scores. Block = (pr, qr, z). S-block(qr,pr)[qc,pc] =
// V[qc,pc]+V[qc+1,pc+1]+V[qc+2,pc+2],  V = sum_i Dtile(qr+i, pr+i)  (elementwise!).
// Only 3 x 8KB of D per block. V stored transposed f32 (odd stride 65 -> lane=qc
// reads conflict-free). Fold over pr-blocks via u64 atomicMax keys (exact
// value-desc + first-index semantics: key = monotone(f32)<<12 | (63-pr)<<6|(63-pc)).
__global__ __launch_bounds__(256) void k_score(const unsigned short* __restrict__ Dbase,
                                               unsigned long long* __restrict__ keys) {
    const int z = blockIdx.z;
    const unsigned short* D = Dbase + (size_t)z * NPIX * NPIX;
    const int pr = blockIdx.x, qr = blockIdx.y;
    const int t = threadIdx.x;

    __shared__ float VT[64 * VSTRIDE + 8];         // 16.7 KB, transposed: VT[b*65+a]

    const int a  = t >> 2;
    const int b0 = (t & 3) * 16;
    float v[16];
#pragma unroll
    for (int e = 0; e < 16; ++e) v[e] = 0.f;
#pragma unroll
    for (int i = 0; i < 3; ++i) {
        const unsigned short* rp =
            D + (size_t)((qr + i) * 64 + a) * NPIX + (pr + i) * 64 + b0;
        uint4 u0 = *(const uint4*)rp;
        uint4 u1 = *(const uint4*)(rp + 8);
        const unsigned* uw = (const unsigned*)&u0;
#pragma unroll
        for (int w = 0; w < 4; ++w) {
            v[2 * w]     += bf16_to_f32((unsigned short)uw[w]);
            v[2 * w + 1] += bf16_to_f32((unsigned short)(uw[w] >> 16));
        }
        const unsigned* uw1 = (const unsigned*)&u1;
#pragma unroll
        for (int w = 0; w < 4; ++w) {
            v[8 + 2 * w]     += bf16_to_f32((unsigned short)uw1[w]);
            v[8 + 2 * w + 1] += bf16_to_f32((unsigned short)(uw1[w] >> 16));
        }
    }
#pragma unroll
    for (int e = 0; e < 16; ++e)
        VT[(b0 + e) * VSTRIDE + a] = v[e];         // 2-way bank alias = free
    __syncthreads();

    const int g = t >> 6, qc = t & 63;
    float best = -1e30f; int bpc = 0;
    const int kmax = (g == 3) ? 14 : 16;           // pc < 62 (wave-uniform trip count)
    for (int k = 0; k < kmax; ++k) {
        int pc = g * 16 + k;
        float s = VT[pc * VSTRIDE + qc]
                + VT[(pc + 1) * VSTRIDE + qc + 1]
                + VT[(pc + 2) * VSTRIDE + qc + 2];
        if (s > best) { best = s; bpc = pc; }      // ascending pc => first-max kept
    }
    if (qc < OH) {
        unsigned u = __float_as_uint(best);
        u = (best >= 0.f) ? (u | 0x80000000u) : ~u;
        unsigned long long key = ((unsigned long long)u << 12)
                               | (unsigned)((63 - pr) << 6) | (unsigned)(63 - bpc);
        atomicMax(&keys[(size_t)z * NPATCH + qr * OH + qc], key);
    }
}

// -------- K4 (k_loss): decode keys -> match; loss via norm expansion --------
__global__ void k_loss(const unsigned short* __restrict__ Dbase,
                       const unsigned long long* __restrict__ keys,
                       const float* __restrict__ ssPb, const float* __restrict__ invPb,
                       const float* __restrict__ ssTb, const float* __restrict__ invTb,
                       float* __restrict__ out) {
    const int z = blockIdx.y;
    const unsigned short* D = Dbase + (size_t)z * NPIX * NPIX;
    const float* ssP  = ssPb  + z * NPIX;
    const float* invP = invPb + z * NPIX;
    const float* ssT  = ssTb  + z * NPIX;
    const float* invT = invTb + z * NPIX;
    int q = blockIdx.x * 256 + threadIdx.x;
    float acc = 0.f;
    if (q < NPATCH) {
        int qr = q / OH, qc = q - qr * OH;
        int qpix = qr * WW + qc;
        unsigned long long key = keys[(size_t)z * NPATCH + q];
        int mpr = 63 - (int)((key >> 6) & 63);
        int mpc = 63 - (int)(key & 63);
        int mpix = mpr * WW + mpc;
#pragma unroll
        for (int i = 0; i < 3; ++i)
#pragma unroll
            for (int j = 0; j < 3; ++j) {
                int off = i * WW + j;
                int y = qpix + off, x = mpix + off;
                float Dv = bf16_to_f32(D[(size_t)y * NPIX + x]);
                float nP = ssP[y] * invP[y];       // = ||p_y||
                float nT = ssT[x] * invT[x];
                acc += ssP[y] + ssT[x] - 2.f * Dv * nP * nT;
            }
    }
#pragma unroll
    for (int s = 32; s > 0; s >>= 1) acc += __shfl_down(acc, s, 64);
    if ((threadIdx.x & 63) == 0)
        atomicAdd(out, acc * (1.f / 35426304.f));  // / (4*3844*2304)
}

// ---------------------------------- launch ----------------------------------
extern "C" void kernel_launch(void* const* d_in, const int* in_sizes, int n_in,
                              void* d_out, int out_size, void* d_ws, size_t ws_size,
                              hipStream_t stream) {
    const float* pred = (const float*)d_in[0];
    const float* tgt  = (const float*)d_in[1];
    char* ws = (char*)d_ws;
    // ws layout (bytes), ws_size = 256 MiB:
    // D(bf16, 4 batches) 128MB | Xn 8MB | Tn 8MB | norms 4x64KB | keys 123KB
    unsigned short*     Dws  = (unsigned short*)(ws);
    __hip_bfloat16*     Xn   = (__hip_bfloat16*)(ws + 134217728);
    __hip_bfloat16*     Tn   = (__hip_bfloat16*)(ws + 142606336);
    float*              ssP  = (float*)(ws + 150994944);
    float*              invP = (float*)(ws + 151060480);
    float*              ssT  = (float*)(ws + 151126016);
    float*              invT = (float*)(ws + 151191552);
    unsigned long long* keys = (unsigned long long*)(ws + 151257088);

    k_prep<<<dim3(64, 8), 256, 0, stream>>>(pred, tgt, Xn, Tn, ssP, invP, ssT, invT,
                                            keys, (float*)d_out);
    k_gemm<<<dim3(32, 32, 4), 256, 0, stream>>>(Xn, Tn, Dws);
    k_score<<<dim3(62, 62, 4), 256, 0, stream>>>(Dws, keys);
    k_loss<<<dim3(16, 4), 256, 0, stream>>>(Dws, keys, ssP, invP, ssT, invT,
                                            (float*)d_out);
}